// Round 3
// baseline (5324.116 us; speedup 1.0000x reference)
//
#include <hip/hip_runtime.h>

// DecoderLSTM (show-attend-tell) for MI355X. R3: the 31-step recurrence is
// fused into ONE persistent kernel (144 blocks, device-scope atomic grid
// barrier) with weight tiles resident in LDS across all steps.
// B=64 T=32 F=512 L=196 E=512 H=512 A=512 V=10000, Tmax=31. Inputs fp32
// (dtype-detected), canonicalized to bf16; bf16 MFMA 16x16x32.

typedef unsigned short ushort_t;
typedef __attribute__((ext_vector_type(8))) short short8;
typedef __attribute__((ext_vector_type(4))) float f32x4;

__device__ __forceinline__ float bf2f(ushort_t u) {
    unsigned x = ((unsigned)u) << 16;
    float f;
    __builtin_memcpy(&f, &x, 4);
    return f;
}
__device__ __forceinline__ ushort_t f2bf(float f) {
    unsigned x;
    __builtin_memcpy(&x, &f, 4);
    unsigned r = (x + 0x7fffu + ((x >> 16) & 1u)) >> 16;
    return (ushort_t)r;
}
__device__ __forceinline__ float sigmoidf_(float x) { return 1.f / (1.f + __expf(-x)); }
__device__ __forceinline__ float tanh_fast(float x) {
    float e = __expf(2.f * x);
    return 1.f - 2.f / (e + 1.f);
}
__device__ __forceinline__ float wred_sum(float v) {
    #pragma unroll
    for (int m = 32; m; m >>= 1) v += __shfl_xor(v, m, 64);
    return v;
}
__device__ __forceinline__ float wred_max(float v) {
    #pragma unroll
    for (int m = 32; m; m >>= 1) v = fmaxf(v, __shfl_xor(v, m, 64));
    return v;
}

// ---- dtype detection ----
__global__ void detect_kernel(const unsigned* __restrict__ feat_raw, int* __restrict__ flag) {
    int lane = threadIdx.x;
    unsigned u = feat_raw[lane];
    unsigned e = (u >> 7) & 0xffu;
    bool bf_like = (e >= 105 && e <= 133);
    unsigned long long m = __ballot(bf_like);
    if (lane == 0) *flag = (__popcll(m) >= 40) ? 0 : 1;  // 1 -> fp32 inputs
}

__global__ void bar_init(unsigned* __restrict__ bar) { bar[threadIdx.x] = 0u; }

#define NCVT 19
struct CvtArgs {
    const void* src[NCVT];
    void* dst[NCVT];
    int n[NCVT];
};

__global__ __launch_bounds__(256) void convert_kernel(CvtArgs a, const int* __restrict__ flag) {
    const int ai = blockIdx.y;
    const int n = a.n[ai];
    const int base = (blockIdx.x * 256 + threadIdx.x) * 8;
    if (base >= n) return;
    ushort_t* dst = (ushort_t*)a.dst[ai];
    if (*flag) {
        const float* s = (const float*)a.src[ai];
        #pragma unroll
        for (int i = 0; i < 8; ++i) {
            int idx = base + i;
            if (idx < n) dst[idx] = f2bf(s[idx]);
        }
    } else {
        const ushort_t* s = (const ushort_t*)a.src[ai];
        #pragma unroll
        for (int i = 0; i < 8; ++i) {
            int idx = base + i;
            if (idx < n) dst[idx] = s[idx];
        }
    }
}

// ---- gather needed embedding rows -> bf16 [31*64, 512] ----
__global__ __launch_bounds__(256) void embrows_kernel(const void* __restrict__ Wemb,
                                                      const int* __restrict__ captions,
                                                      const int* __restrict__ flag,
                                                      ushort_t* __restrict__ emb_c) {
    const int tb = blockIdx.x;
    const int t = tb >> 6, b = tb & 63;
    const int cap = captions[b * 32 + t];
    const int e0 = threadIdx.x;
    if (*flag) {
        const float* s = (const float*)Wemb + cap * 512;
        emb_c[tb * 512 + e0] = f2bf(s[e0]);
        emb_c[tb * 512 + e0 + 256] = f2bf(s[e0 + 256]);
    } else {
        const ushort_t* s = (const ushort_t*)Wemb + cap * 512;
        emb_c[tb * 512 + e0] = s[e0];
        emb_c[tb * 512 + e0 + 256] = s[e0 + 256];
    }
}

// ---- generic 64x64 MFMA tile (used by pre/post GEMMs only) ----
template <class AROW, class BROW, class EPI>
__device__ __forceinline__ void gemm_tile(AROW arow, BROW brow, EPI epi) {
    __shared__ __align__(16) ushort_t As[64][40];
    __shared__ __align__(16) ushort_t Bs[64][40];
    const int tid = threadIdx.x;
    const int row = tid >> 2, ks = (tid & 3) << 3;
    const int wave = tid >> 6, lane = tid & 63;
    const int quad = lane >> 4, l15 = lane & 15;
    f32x4 acc[4];
    #pragma unroll
    for (int s = 0; s < 4; ++s) acc[s] = (f32x4){0.f, 0.f, 0.f, 0.f};
    const ushort_t* ap = arow(row);
    const ushort_t* bp = brow(row);
    for (int k0 = 0; k0 < 512; k0 += 32) {
        short8 av = {0, 0, 0, 0, 0, 0, 0, 0};
        short8 bv = {0, 0, 0, 0, 0, 0, 0, 0};
        if (ap) av = *(const short8*)(ap + k0 + ks);
        if (bp) bv = *(const short8*)(bp + k0 + ks);
        __syncthreads();
        *(short8*)&As[row][ks] = av;
        *(short8*)&Bs[row][ks] = bv;
        __syncthreads();
        short8 af = *(const short8*)&As[(wave << 4) + l15][quad << 3];
        #pragma unroll
        for (int s = 0; s < 4; ++s) {
            short8 bfr = *(const short8*)&Bs[(s << 4) + l15][quad << 3];
            acc[s] = __builtin_amdgcn_mfma_f32_16x16x32_bf16(af, bfr, acc[s], 0, 0, 0);
        }
    }
    epi((wave << 4) + (quad << 2), l15, acc);
}

// ---- mean over L of features [B, F, L] -> bf16 [B, F] ----
__global__ __launch_bounds__(256) void mean_kernel(const ushort_t* __restrict__ features,
                                                   ushort_t* __restrict__ mean_bf) {
    const int b = blockIdx.x;
    const int wave = threadIdx.x >> 6, lane = threadIdx.x & 63;
    const ushort_t* fb = features + b * 512 * 196;
    for (int f = wave; f < 512; f += 4) {
        const ushort_t* r = fb + f * 196;
        float s = bf2f(r[lane]) + bf2f(r[lane + 64]) + bf2f(r[lane + 128]);
        if (lane < 4) s += bf2f(r[lane + 192]);
        s = wred_sum(s);
        if (lane == 0) mean_bf[b * 512 + f] = f2bf(s * (1.f / 196.f));
    }
}

// ---- h0 / c0 ----
__global__ __launch_bounds__(256) void init_kernel(
    const ushort_t* __restrict__ mean_bf, const ushort_t* __restrict__ Winh,
    const ushort_t* __restrict__ binh, const ushort_t* __restrict__ Winc,
    const ushort_t* __restrict__ binc, ushort_t* __restrict__ h_bf,
    float* __restrict__ cbuf) {
    const int n0 = blockIdx.x << 6;
    gemm_tile(
        [&](int r) { return mean_bf + r * 512; },
        [&](int r) {
            int n = n0 + r;
            return (n < 512) ? (Winh + n * 512) : (Winc + (n - 512) * 512);
        },
        [&](int mb, int l15, const f32x4* acc) {
            #pragma unroll
            for (int s = 0; s < 4; ++s) {
                int n = n0 + (s << 4) + l15;
                #pragma unroll
                for (int r = 0; r < 4; ++r) {
                    int b = mb + r;
                    if (n < 512)
                        h_bf[b * 512 + n] = f2bf(acc[s][r] + bf2f(binh[n]));
                    else
                        cbuf[b * 512 + (n - 512)] = acc[s][r] + bf2f(binc[n - 512]);
                }
            }
        });
}

// ---- en_att = feat_r @ W_enc.T + b_enc -> bf16 [12544, 512] ----
__global__ __launch_bounds__(256) void enatt_kernel(const ushort_t* __restrict__ feat,
                                                    const ushort_t* __restrict__ Wenc,
                                                    const ushort_t* __restrict__ benc,
                                                    ushort_t* __restrict__ en_att) {
    const int m0 = blockIdx.y << 6, n0 = blockIdx.x << 6;
    gemm_tile(
        [&](int r) { return feat + (m0 + r) * 512; },
        [&](int r) { return Wenc + (n0 + r) * 512; },
        [&](int mb, int l15, const f32x4* acc) {
            #pragma unroll
            for (int s = 0; s < 4; ++s) {
                int n = n0 + (s << 4) + l15;
                float bias = bf2f(benc[n]);
                #pragma unroll
                for (int r = 0; r < 4; ++r) {
                    int m = m0 + mb + r;
                    en_att[m * 512 + n] = f2bf(acc[s][r] + bias);
                }
            }
        });
}

// ---- ec[t,b,j] = emb_row @ W_ih[:, :512].T + b_ih + b_hh -> fp32 ----
__global__ __launch_bounds__(256) void ec_kernel(const ushort_t* __restrict__ emb_c,
                                                 const ushort_t* __restrict__ Wih,
                                                 const ushort_t* __restrict__ bih,
                                                 const ushort_t* __restrict__ bhh,
                                                 float* __restrict__ ec) {
    const int t = blockIdx.y, n0 = blockIdx.x << 6;
    gemm_tile(
        [&](int r) { return emb_c + (t * 64 + r) * 512; },
        [&](int r) { return Wih + (n0 + r) * 1024; },
        [&](int mb, int l15, const f32x4* acc) {
            #pragma unroll
            for (int s = 0; s < 4; ++s) {
                int j = n0 + (s << 4) + l15;
                float bias = bf2f(bih[j]) + bf2f(bhh[j]);
                #pragma unroll
                for (int r = 0; r < 4; ++r) {
                    int b = mb + r;
                    ec[(t * 64 + b) * 2048 + j] = acc[s][r] + bias;
                }
            }
        });
}

// ================== fused persistent recurrence kernel ==================
// Grid: 144 blocks x 256 threads. Blocks 0..47: stepA GEMM tiles (resident
// LDS weights [Wdec;Wfb;Whh]); 48..79: stepC GEMM tiles (W_ih z-cols,
// [i,f,g,o]x16 row order); 80..143: attention for batch b = bid-80.
#define NBLK 144

__device__ __forceinline__ void grid_barrier(unsigned* bar, unsigned gen) {
    __syncthreads();
    if (threadIdx.x == 0) {
        __threadfence();
        int grp = blockIdx.x & 7;
        unsigned prev = __hip_atomic_fetch_add(&bar[grp << 5], 1u, __ATOMIC_ACQ_REL,
                                               __HIP_MEMORY_SCOPE_AGENT);
        if (prev == (NBLK / 8) - 1) {
            __hip_atomic_store(&bar[grp << 5], 0u, __ATOMIC_RELAXED,
                               __HIP_MEMORY_SCOPE_AGENT);
            unsigned pr = __hip_atomic_fetch_add(&bar[256], 1u, __ATOMIC_ACQ_REL,
                                                 __HIP_MEMORY_SCOPE_AGENT);
            if (pr == 7) {
                __hip_atomic_store(&bar[256], 0u, __ATOMIC_RELAXED,
                                   __HIP_MEMORY_SCOPE_AGENT);
                __hip_atomic_store(&bar[288], gen + 1, __ATOMIC_RELEASE,
                                   __HIP_MEMORY_SCOPE_AGENT);
            }
        }
        long cap = 0;
        while (__hip_atomic_load(&bar[288], __ATOMIC_ACQUIRE,
                                 __HIP_MEMORY_SCOPE_AGENT) == gen) {
            __builtin_amdgcn_s_sleep(2);
            if (++cap > (1l << 22)) break;  // graceful bail: wrong answer, not hang
        }
        __threadfence();
    }
    __syncthreads();
}

__global__ __launch_bounds__(256) void fused_loop(
    const ushort_t* __restrict__ Wdec_c, const ushort_t* __restrict__ bdec_c,
    const ushort_t* __restrict__ Wfb_c, const ushort_t* __restrict__ bfb_c,
    const ushort_t* __restrict__ Whh_c, const ushort_t* __restrict__ Wih_c,
    const ushort_t* __restrict__ wfull_c, const ushort_t* __restrict__ bfull_c,
    const ushort_t* __restrict__ en_att, const ushort_t* __restrict__ feat_c,
    const float* __restrict__ ec, const int* __restrict__ lengths,
    const int* __restrict__ flag, void* __restrict__ out_base,
    ushort_t* __restrict__ h_bf, float* __restrict__ cbuf, float* __restrict__ de,
    float* __restrict__ fgate, float* __restrict__ hh, ushort_t* __restrict__ z_bf,
    ushort_t* __restrict__ H_all, unsigned* __restrict__ bar) {
    __shared__ __align__(16) char smem[65536];
    const int bid = blockIdx.x, tid = threadIdx.x;
    const int wave = tid >> 6, lane = tid & 63;
    const int quad = lane >> 4, l15 = lane & 15;
    ushort_t* tile = (ushort_t*)smem;

    // ---- one-time staging ----
    if (bid < 80) {
        const int row = tid >> 2;
        const ushort_t* src;
        if (bid < 48) {
            int n = (bid << 6) + row;
            src = (n < 512) ? (Wdec_c + n * 512)
                            : ((n < 1024) ? (Wfb_c + (n - 512) * 512)
                                          : (Whh_c + (n - 1024) * 512));
        } else {
            int nt = bid - 48;
            int j = (row >> 4) * 512 + nt * 16 + (row & 15);
            src = Wih_c + j * 1024 + 512;  // z-columns of W_ih
        }
        #pragma unroll
        for (int i = 0; i < 16; ++i) {
            int cb = ((tid & 3) << 4) + i;
            short8 v = *(const short8*)(src + (cb << 3));
            *(short8*)(tile + row * 512 + (((cb ^ (row & 15))) << 3)) = v;
        }
    } else {
        float* wf_s = ((float*)smem) + 512;
        wf_s[tid] = bf2f(wfull_c[tid]);
        wf_s[tid + 256] = bf2f(wfull_c[tid + 256]);
    }
    __syncthreads();

    const int f32o = *flag;
    const float bf0 = bf2f(bfull_c[0]);
    const int b_B = bid - 80;
    const int mylen = (bid >= 80) ? lengths[b_B] : 0;
    unsigned gen = 0;

    for (int t = 0; t < 31; ++t) {
        // ================= phase A =================
        if (bid < 48) {
            f32x4 acc[4];
            #pragma unroll
            for (int s = 0; s < 4; ++s) acc[s] = (f32x4){0.f, 0.f, 0.f, 0.f};
            const ushort_t* ar = h_bf + ((wave << 4) + l15) * 512 + (quad << 3);
            short8 af[16];
            #pragma unroll
            for (int ki = 0; ki < 16; ++ki) af[ki] = *(const short8*)(ar + (ki << 5));
            #pragma unroll
            for (int ki = 0; ki < 16; ++ki) {
                int cb = (ki << 2) + quad;
                #pragma unroll
                for (int s = 0; s < 4; ++s) {
                    short8 bfr = *(const short8*)(tile + ((s << 4) + l15) * 512 +
                                                  ((cb ^ l15) << 3));
                    acc[s] = __builtin_amdgcn_mfma_f32_16x16x32_bf16(af[ki], bfr,
                                                                     acc[s], 0, 0, 0);
                }
            }
            const int n0 = bid << 6, mb = (wave << 4) + (quad << 2);
            #pragma unroll
            for (int s = 0; s < 4; ++s) {
                int n = n0 + (s << 4) + l15;
                #pragma unroll
                for (int r = 0; r < 4; ++r) {
                    int b = mb + r;
                    float v = acc[s][r];
                    if (n < 512)
                        de[b * 512 + n] = v + bf2f(bdec_c[n]);
                    else if (n < 1024)
                        fgate[b * 512 + (n - 512)] = sigmoidf_(v + bf2f(bfb_c[n - 512]));
                    else
                        hh[b * 2048 + (n - 1024)] = v;
                }
            }
        }
        grid_barrier(bar, gen++);

        // ================= phase B =================
        if (bid >= 80) {
            float* de_s = (float*)smem;
            float* wf_s = de_s + 512;
            float* fullv = wf_s + 512;
            float* red = fullv + 196;
            const size_t aoff = 19840000ull + ((size_t)b_B * 31 + t) * 196;
            const bool active = (mylen - 1) > t;
            if (!active) {
                if (tid < 196) {
                    if (f32o) ((float*)out_base)[aoff + tid] = 0.f;
                    else ((ushort_t*)out_base)[aoff + tid] = 0;
                }
            } else {
                de_s[tid] = de[b_B * 512 + tid];
                de_s[tid + 256] = de[b_B * 512 + tid + 256];
                __syncthreads();
                const ushort_t* ea = en_att + b_B * 196 * 512;
                for (int l = wave; l < 196; l += 4) {
                    const ushort_t* er = ea + l * 512;
                    float acc = 0.f;
                    #pragma unroll
                    for (int s = 0; s < 8; ++s) {
                        int a = s * 64 + lane;
                        float x = bf2f(er[a]) + de_s[a];
                        acc += tanh_fast(x) * wf_s[a];
                    }
                    acc = wred_sum(acc);
                    if (lane == 0) fullv[l] = acc + bf0;
                }
                __syncthreads();
                float v = (tid < 196) ? fullv[tid] : -1e30f;
                float wm = wred_max(v);
                if (lane == 0) red[wave] = wm;
                __syncthreads();
                float mx = fmaxf(fmaxf(red[0], red[1]), fmaxf(red[2], red[3]));
                float e = (tid < 196) ? __expf(v - mx) : 0.f;
                float sw = wred_sum(e);
                if (lane == 0) red[4 + wave] = sw;
                __syncthreads();
                float inv = 1.f / (red[4] + red[5] + red[6] + red[7]);
                if (tid < 196) {
                    float a = e * inv;
                    fullv[tid] = a;
                    if (f32o) ((float*)out_base)[aoff + tid] = a;
                    else ((ushort_t*)out_base)[aoff + tid] = f2bf(a);
                }
                __syncthreads();
                const ushort_t* fr = feat_c + b_B * 196 * 512;
                float z1 = 0.f, z2 = 0.f;
                for (int l = 0; l < 196; ++l) {
                    float a = fullv[l];
                    z1 += a * bf2f(fr[l * 512 + tid]);
                    z2 += a * bf2f(fr[l * 512 + tid + 256]);
                }
                z1 *= fgate[b_B * 512 + tid];
                z2 *= fgate[b_B * 512 + tid + 256];
                z_bf[b_B * 512 + tid] = f2bf(z1);
                z_bf[b_B * 512 + tid + 256] = f2bf(z2);
                __syncthreads();
            }
        }
        grid_barrier(bar, gen++);

        // ================= phase C =================
        if (bid >= 48 && bid < 80) {
            f32x4 acc[4];
            #pragma unroll
            for (int s = 0; s < 4; ++s) acc[s] = (f32x4){0.f, 0.f, 0.f, 0.f};
            const ushort_t* ar = z_bf + ((wave << 4) + l15) * 512 + (quad << 3);
            short8 af[16];
            #pragma unroll
            for (int ki = 0; ki < 16; ++ki) af[ki] = *(const short8*)(ar + (ki << 5));
            #pragma unroll
            for (int ki = 0; ki < 16; ++ki) {
                int cb = (ki << 2) + quad;
                #pragma unroll
                for (int s = 0; s < 4; ++s) {
                    short8 bfr = *(const short8*)(tile + ((s << 4) + l15) * 512 +
                                                  ((cb ^ l15) << 3));
                    acc[s] = __builtin_amdgcn_mfma_f32_16x16x32_bf16(af[ki], bfr,
                                                                     acc[s], 0, 0, 0);
                }
            }
            const int nt = bid - 48;
            const int dim = (nt << 4) + l15;
            const int mb = (wave << 4) + (quad << 2);
            #pragma unroll
            for (int r = 0; r < 4; ++r) {
                int b = mb + r;
                int eb = (t * 64 + b) * 2048, hb = b * 2048;
                float ig = acc[0][r] + ec[eb + dim] + hh[hb + dim];
                float fg = acc[1][r] + ec[eb + 512 + dim] + hh[hb + 512 + dim];
                float gg = acc[2][r] + ec[eb + 1024 + dim] + hh[hb + 1024 + dim];
                float og = acc[3][r] + ec[eb + 1536 + dim] + hh[hb + 1536 + dim];
                float co = cbuf[b * 512 + dim];
                float cn = sigmoidf_(fg) * co + sigmoidf_(ig) * tanh_fast(gg);
                float hn = sigmoidf_(og) * tanh_fast(cn);
                H_all[(t * 64 + b) * 512 + dim] = f2bf(hn);
                if (lengths[b] - 1 > t) {
                    cbuf[b * 512 + dim] = cn;
                    h_bf[b * 512 + dim] = f2bf(hn);
                }
            }
        }
        grid_barrier(bar, gen++);
    }
}

// ---- preds = H_all @ W_out.T + b_out, ragged-masked ----
__global__ __launch_bounds__(256) void preds_kernel(
    const ushort_t* __restrict__ H_all, const ushort_t* __restrict__ Wout,
    const ushort_t* __restrict__ bout, const int* __restrict__ lengths,
    const int* __restrict__ flag, void* __restrict__ out_base) {
    const int t = blockIdx.y, n0 = blockIdx.x << 6;
    const int f32o = *flag;
    gemm_tile(
        [&](int r) { return H_all + (t * 64 + r) * 512; },
        [&](int r) -> const ushort_t* {
            int n = n0 + r;
            return (n < 10000) ? (Wout + n * 512) : (const ushort_t*)nullptr;
        },
        [&](int mb, int l15, const f32x4* acc) {
            #pragma unroll
            for (int s = 0; s < 4; ++s) {
                int n = n0 + (s << 4) + l15;
                if (n >= 10000) continue;
                float bias = bf2f(bout[n]);
                #pragma unroll
                for (int r = 0; r < 4; ++r) {
                    int b = mb + r;
                    bool act = lengths[b] > t + 1;
                    float val = act ? (acc[s][r] + bias) : 0.f;
                    size_t off = (size_t)b * 310000 + t * 10000 + n;
                    if (f32o) ((float*)out_base)[off] = val;
                    else ((ushort_t*)out_base)[off] = act ? f2bf(val) : (ushort_t)0;
                }
            }
        });
}

extern "C" void kernel_launch(void* const* d_in, const int* in_sizes, int n_in,
                              void* d_out, int out_size, void* d_ws, size_t ws_size,
                              hipStream_t stream) {
    const void* features = d_in[0];
    const int* captions = (const int*)d_in[1];
    const int* lengths = (const int*)d_in[2];
    const void* W_emb = d_in[3];

    char* ws = (char*)d_ws;
    size_t o = 0;
    auto alloc = [&](size_t bytes) {
        size_t r = o;
        o += (bytes + 255) & ~(size_t)255;
        return r;
    };
    ushort_t* feat_c  = (ushort_t*)(ws + alloc(6422528ull * 2));
    ushort_t* Wenc_c  = (ushort_t*)(ws + alloc(262144ull * 2));
    ushort_t* benc_c  = (ushort_t*)(ws + alloc(512 * 2));
    ushort_t* Wdec_c  = (ushort_t*)(ws + alloc(262144ull * 2));
    ushort_t* bdec_c  = (ushort_t*)(ws + alloc(512 * 2));
    ushort_t* wfull_c = (ushort_t*)(ws + alloc(512 * 2));
    ushort_t* bfull_c = (ushort_t*)(ws + alloc(2));
    ushort_t* Wfb_c   = (ushort_t*)(ws + alloc(262144ull * 2));
    ushort_t* bfb_c   = (ushort_t*)(ws + alloc(512 * 2));
    ushort_t* Wih_c   = (ushort_t*)(ws + alloc(2097152ull * 2));
    ushort_t* Whh_c   = (ushort_t*)(ws + alloc(1048576ull * 2));
    ushort_t* bih_c   = (ushort_t*)(ws + alloc(2048 * 2));
    ushort_t* bhh_c   = (ushort_t*)(ws + alloc(2048 * 2));
    ushort_t* Wout_c  = (ushort_t*)(ws + alloc(5120000ull * 2));
    ushort_t* bout_c  = (ushort_t*)(ws + alloc(10000 * 2));
    ushort_t* Winh_c  = (ushort_t*)(ws + alloc(262144ull * 2));
    ushort_t* binh_c  = (ushort_t*)(ws + alloc(512 * 2));
    ushort_t* Winc_c  = (ushort_t*)(ws + alloc(262144ull * 2));
    ushort_t* binc_c  = (ushort_t*)(ws + alloc(512 * 2));
    ushort_t* emb_c   = (ushort_t*)(ws + alloc(1984ull * 512 * 2));
    ushort_t* en_att  = (ushort_t*)(ws + alloc(12544ull * 512 * 2));
    float*    ec      = (float*)(ws + alloc(1984ull * 2048 * 4));
    ushort_t* H_all   = (ushort_t*)(ws + alloc(1984ull * 512 * 2));
    ushort_t* h_bf    = (ushort_t*)(ws + alloc(64 * 512 * 2));
    float*    cbuf    = (float*)(ws + alloc(64 * 512 * 4));
    float*    de      = (float*)(ws + alloc(64 * 512 * 4));
    float*    fgate   = (float*)(ws + alloc(64 * 512 * 4));
    float*    hh      = (float*)(ws + alloc(64ull * 2048 * 4));
    ushort_t* z_bf    = (ushort_t*)(ws + alloc(64 * 512 * 2));
    ushort_t* mean_bf = (ushort_t*)(ws + alloc(64 * 512 * 2));
    int*      flag    = (int*)(ws + alloc(256));
    unsigned* bar     = (unsigned*)(ws + alloc(2048));

    detect_kernel<<<1, 64, 0, stream>>>((const unsigned*)features, flag);
    bar_init<<<1, 512, 0, stream>>>(bar);

    CvtArgs ca;
    const void* srcs[NCVT] = {features, d_in[4], d_in[5], d_in[6], d_in[7], d_in[8],
                              d_in[9], d_in[10], d_in[11], d_in[12], d_in[13], d_in[14],
                              d_in[15], d_in[16], d_in[17], d_in[18], d_in[19], d_in[20],
                              d_in[21]};
    void* dsts[NCVT] = {feat_c, Wenc_c, benc_c, Wdec_c, bdec_c, wfull_c, bfull_c,
                        Wfb_c, bfb_c, Wih_c, Whh_c, bih_c, bhh_c, Wout_c, bout_c,
                        Winh_c, binh_c, Winc_c, binc_c};
    int ns[NCVT] = {6422528, 262144, 512, 262144, 512, 512, 1, 262144, 512,
                    2097152, 1048576, 2048, 2048, 5120000, 10000, 262144, 512,
                    262144, 512};
    for (int i = 0; i < NCVT; ++i) {
        ca.src[i] = srcs[i];
        ca.dst[i] = dsts[i];
        ca.n[i] = ns[i];
    }
    convert_kernel<<<dim3(3136, NCVT), 256, 0, stream>>>(ca, flag);
    embrows_kernel<<<1984, 256, 0, stream>>>(W_emb, captions, flag, emb_c);

    mean_kernel<<<64, 256, 0, stream>>>(feat_c, mean_bf);
    init_kernel<<<16, 256, 0, stream>>>(mean_bf, Winh_c, binh_c, Winc_c, binc_c,
                                        h_bf, cbuf);
    enatt_kernel<<<dim3(8, 196), 256, 0, stream>>>(feat_c, Wenc_c, benc_c, en_att);
    ec_kernel<<<dim3(32, 31), 256, 0, stream>>>(emb_c, Wih_c, bih_c, bhh_c, ec);

    fused_loop<<<NBLK, 256, 0, stream>>>(Wdec_c, bdec_c, Wfb_c, bfb_c, Whh_c, Wih_c,
                                         wfull_c, bfull_c, en_att, feat_c, ec,
                                         lengths, flag, d_out, h_bf, cbuf, de, fgate,
                                         hh, z_bf, H_all, bar);

    preds_kernel<<<dim3(157, 31), 256, 0, stream>>>(H_all, Wout_c, bout_c, lengths,
                                                    flag, d_out);
}

// Round 4
// 2442.782 us; speedup vs baseline: 2.1795x; 2.1795x over previous
//
#include <hip/hip_runtime.h>

// DecoderLSTM (show-attend-tell) for MI355X. R4: persistent fused recurrence
// with a CHEAP grid barrier: relaxed-atomic spin (no per-poll L2 inv),
// monotonic generation counters, role-based release/acquire fences (one wbl2
// per producer, one inv per consumer per barrier). B blocks use per-access
// relaxed agent atomic loads for de/fgate so their L2 stays warm (en_att/feat
// cached across all 31 steps). preds_kernel: LDS-resident Wout tile x 8 t.
// B=64 T=32 F=512 L=196 E=512 H=512 A=512 V=10000, Tmax=31.

typedef unsigned short ushort_t;
typedef __attribute__((ext_vector_type(8))) short short8;
typedef __attribute__((ext_vector_type(4))) float f32x4;

__device__ __forceinline__ float bf2f(ushort_t u) {
    unsigned x = ((unsigned)u) << 16;
    float f;
    __builtin_memcpy(&f, &x, 4);
    return f;
}
__device__ __forceinline__ ushort_t f2bf(float f) {
    unsigned x;
    __builtin_memcpy(&x, &f, 4);
    unsigned r = (x + 0x7fffu + ((x >> 16) & 1u)) >> 16;
    return (ushort_t)r;
}
__device__ __forceinline__ float sigmoidf_(float x) { return 1.f / (1.f + __expf(-x)); }
__device__ __forceinline__ float tanh_fast(float x) {
    float e = __expf(2.f * x);
    return 1.f - 2.f / (e + 1.f);
}
__device__ __forceinline__ float wred_sum(float v) {
    #pragma unroll
    for (int m = 32; m; m >>= 1) v += __shfl_xor(v, m, 64);
    return v;
}
__device__ __forceinline__ float wred_max(float v) {
    #pragma unroll
    for (int m = 32; m; m >>= 1) v = fmaxf(v, __shfl_xor(v, m, 64));
    return v;
}
__device__ __forceinline__ float agent_ldf(const float* p) {
    return __hip_atomic_load((float*)p, __ATOMIC_RELAXED, __HIP_MEMORY_SCOPE_AGENT);
}

// ---- dtype detection ----
__global__ void detect_kernel(const unsigned* __restrict__ feat_raw, int* __restrict__ flag) {
    int lane = threadIdx.x;
    unsigned u = feat_raw[lane];
    unsigned e = (u >> 7) & 0xffu;
    bool bf_like = (e >= 105 && e <= 133);
    unsigned long long m = __ballot(bf_like);
    if (lane == 0) *flag = (__popcll(m) >= 40) ? 0 : 1;  // 1 -> fp32 inputs
}

__global__ void bar_init(unsigned* __restrict__ bar) { bar[threadIdx.x] = 0u; }

#define NCVT 19
struct CvtArgs {
    const void* src[NCVT];
    void* dst[NCVT];
    int n[NCVT];
};

__global__ __launch_bounds__(256) void convert_kernel(CvtArgs a, const int* __restrict__ flag) {
    const int ai = blockIdx.y;
    const int n = a.n[ai];
    const int base = (blockIdx.x * 256 + threadIdx.x) * 8;
    if (base >= n) return;
    ushort_t* dst = (ushort_t*)a.dst[ai];
    if (*flag) {
        const float* s = (const float*)a.src[ai];
        #pragma unroll
        for (int i = 0; i < 8; ++i) {
            int idx = base + i;
            if (idx < n) dst[idx] = f2bf(s[idx]);
        }
    } else {
        const ushort_t* s = (const ushort_t*)a.src[ai];
        #pragma unroll
        for (int i = 0; i < 8; ++i) {
            int idx = base + i;
            if (idx < n) dst[idx] = s[idx];
        }
    }
}

// ---- gather needed embedding rows -> bf16 [31*64, 512] ----
__global__ __launch_bounds__(256) void embrows_kernel(const void* __restrict__ Wemb,
                                                      const int* __restrict__ captions,
                                                      const int* __restrict__ flag,
                                                      ushort_t* __restrict__ emb_c) {
    const int tb = blockIdx.x;
    const int t = tb >> 6, b = tb & 63;
    const int cap = captions[b * 32 + t];
    const int e0 = threadIdx.x;
    if (*flag) {
        const float* s = (const float*)Wemb + cap * 512;
        emb_c[tb * 512 + e0] = f2bf(s[e0]);
        emb_c[tb * 512 + e0 + 256] = f2bf(s[e0 + 256]);
    } else {
        const ushort_t* s = (const ushort_t*)Wemb + cap * 512;
        emb_c[tb * 512 + e0] = s[e0];
        emb_c[tb * 512 + e0 + 256] = s[e0 + 256];
    }
}

// ---- generic 64x64 MFMA tile (pre-pass GEMMs) ----
template <class AROW, class BROW, class EPI>
__device__ __forceinline__ void gemm_tile(AROW arow, BROW brow, EPI epi) {
    __shared__ __align__(16) ushort_t As[64][40];
    __shared__ __align__(16) ushort_t Bs[64][40];
    const int tid = threadIdx.x;
    const int row = tid >> 2, ks = (tid & 3) << 3;
    const int wave = tid >> 6, lane = tid & 63;
    const int quad = lane >> 4, l15 = lane & 15;
    f32x4 acc[4];
    #pragma unroll
    for (int s = 0; s < 4; ++s) acc[s] = (f32x4){0.f, 0.f, 0.f, 0.f};
    const ushort_t* ap = arow(row);
    const ushort_t* bp = brow(row);
    for (int k0 = 0; k0 < 512; k0 += 32) {
        short8 av = {0, 0, 0, 0, 0, 0, 0, 0};
        short8 bv = {0, 0, 0, 0, 0, 0, 0, 0};
        if (ap) av = *(const short8*)(ap + k0 + ks);
        if (bp) bv = *(const short8*)(bp + k0 + ks);
        __syncthreads();
        *(short8*)&As[row][ks] = av;
        *(short8*)&Bs[row][ks] = bv;
        __syncthreads();
        short8 af = *(const short8*)&As[(wave << 4) + l15][quad << 3];
        #pragma unroll
        for (int s = 0; s < 4; ++s) {
            short8 bfr = *(const short8*)&Bs[(s << 4) + l15][quad << 3];
            acc[s] = __builtin_amdgcn_mfma_f32_16x16x32_bf16(af, bfr, acc[s], 0, 0, 0);
        }
    }
    epi((wave << 4) + (quad << 2), l15, acc);
}

// ---- mean over L of features [B, F, L] -> bf16 [B, F] ----
__global__ __launch_bounds__(256) void mean_kernel(const ushort_t* __restrict__ features,
                                                   ushort_t* __restrict__ mean_bf) {
    const int b = blockIdx.x;
    const int wave = threadIdx.x >> 6, lane = threadIdx.x & 63;
    const ushort_t* fb = features + b * 512 * 196;
    for (int f = wave; f < 512; f += 4) {
        const ushort_t* r = fb + f * 196;
        float s = bf2f(r[lane]) + bf2f(r[lane + 64]) + bf2f(r[lane + 128]);
        if (lane < 4) s += bf2f(r[lane + 192]);
        s = wred_sum(s);
        if (lane == 0) mean_bf[b * 512 + f] = f2bf(s * (1.f / 196.f));
    }
}

// ---- h0 / c0 ----
__global__ __launch_bounds__(256) void init_kernel(
    const ushort_t* __restrict__ mean_bf, const ushort_t* __restrict__ Winh,
    const ushort_t* __restrict__ binh, const ushort_t* __restrict__ Winc,
    const ushort_t* __restrict__ binc, ushort_t* __restrict__ h_bf,
    float* __restrict__ cbuf) {
    const int n0 = blockIdx.x << 6;
    gemm_tile(
        [&](int r) { return mean_bf + r * 512; },
        [&](int r) {
            int n = n0 + r;
            return (n < 512) ? (Winh + n * 512) : (Winc + (n - 512) * 512);
        },
        [&](int mb, int l15, const f32x4* acc) {
            #pragma unroll
            for (int s = 0; s < 4; ++s) {
                int n = n0 + (s << 4) + l15;
                #pragma unroll
                for (int r = 0; r < 4; ++r) {
                    int b = mb + r;
                    if (n < 512)
                        h_bf[b * 512 + n] = f2bf(acc[s][r] + bf2f(binh[n]));
                    else
                        cbuf[b * 512 + (n - 512)] = acc[s][r] + bf2f(binc[n - 512]);
                }
            }
        });
}

// ---- en_att = feat_r @ W_enc.T + b_enc -> bf16 [12544, 512] ----
__global__ __launch_bounds__(256) void enatt_kernel(const ushort_t* __restrict__ feat,
                                                    const ushort_t* __restrict__ Wenc,
                                                    const ushort_t* __restrict__ benc,
                                                    ushort_t* __restrict__ en_att) {
    const int m0 = blockIdx.y << 6, n0 = blockIdx.x << 6;
    gemm_tile(
        [&](int r) { return feat + (m0 + r) * 512; },
        [&](int r) { return Wenc + (n0 + r) * 512; },
        [&](int mb, int l15, const f32x4* acc) {
            #pragma unroll
            for (int s = 0; s < 4; ++s) {
                int n = n0 + (s << 4) + l15;
                float bias = bf2f(benc[n]);
                #pragma unroll
                for (int r = 0; r < 4; ++r) {
                    int m = m0 + mb + r;
                    en_att[m * 512 + n] = f2bf(acc[s][r] + bias);
                }
            }
        });
}

// ---- ec[t,b,j] = emb_row @ W_ih[:, :512].T + b_ih + b_hh -> fp32 ----
__global__ __launch_bounds__(256) void ec_kernel(const ushort_t* __restrict__ emb_c,
                                                 const ushort_t* __restrict__ Wih,
                                                 const ushort_t* __restrict__ bih,
                                                 const ushort_t* __restrict__ bhh,
                                                 float* __restrict__ ec) {
    const int t = blockIdx.y, n0 = blockIdx.x << 6;
    gemm_tile(
        [&](int r) { return emb_c + (t * 64 + r) * 512; },
        [&](int r) { return Wih + (n0 + r) * 1024; },
        [&](int mb, int l15, const f32x4* acc) {
            #pragma unroll
            for (int s = 0; s < 4; ++s) {
                int j = n0 + (s << 4) + l15;
                float bias = bf2f(bih[j]) + bf2f(bhh[j]);
                #pragma unroll
                for (int r = 0; r < 4; ++r) {
                    int b = mb + r;
                    ec[(t * 64 + b) * 2048 + j] = acc[s][r] + bias;
                }
            }
        });
}

// ================== fused persistent recurrence kernel ==================
// 144 blocks x 256. 0..47: stepA GEMM (LDS-resident [Wdec;Wfb;Whh] tile);
// 48..79: stepC GEMM (LDS-resident W_ih z-cols, [i,f,g,o]x16 row order);
// 80..143: attention for batch b = bid-80.
#define NBLK 144

// Monotonic-counter tree barrier. bar lines (32 uints each): [g*32] g=0..7
// group arrival counters; [256] second level; [(9+g)*32] generation bcast.
// Spin = RELAXED agent loads (no L2 inv per poll). rel/acq: one wbl2 / one
// inv per block per barrier, only where the role needs it.
__device__ __forceinline__ void grid_barrier(unsigned* bar, unsigned gen,
                                             bool rel, bool acq) {
    __syncthreads();
    if (threadIdx.x == 0) {
        if (rel) __builtin_amdgcn_fence(__ATOMIC_RELEASE, "agent");
        const int grp = blockIdx.x & 7;
        unsigned prev = __hip_atomic_fetch_add(&bar[grp << 5], 1u, __ATOMIC_RELAXED,
                                               __HIP_MEMORY_SCOPE_AGENT);
        if (prev == (gen + 1) * (NBLK / 8) - 1) {
            unsigned pr = __hip_atomic_fetch_add(&bar[8 << 5], 1u, __ATOMIC_RELAXED,
                                                 __HIP_MEMORY_SCOPE_AGENT);
            if (pr == (gen + 1) * 8 - 1) {
                #pragma unroll
                for (int g = 0; g < 8; ++g)
                    __hip_atomic_store(&bar[(9 + g) << 5], gen + 1, __ATOMIC_RELAXED,
                                       __HIP_MEMORY_SCOPE_AGENT);
            }
        }
        long cap = 0;
        while (__hip_atomic_load(&bar[(9 + grp) << 5], __ATOMIC_RELAXED,
                                 __HIP_MEMORY_SCOPE_AGENT) <= gen) {
            __builtin_amdgcn_s_sleep(2);
            if (++cap > (1l << 22)) break;  // bail -> wrong answer, not hang
        }
        if (acq) __builtin_amdgcn_fence(__ATOMIC_ACQUIRE, "agent");
    }
    __syncthreads();
}

__global__ __launch_bounds__(256) void fused_loop(
    const ushort_t* __restrict__ Wdec_c, const ushort_t* __restrict__ bdec_c,
    const ushort_t* __restrict__ Wfb_c, const ushort_t* __restrict__ bfb_c,
    const ushort_t* __restrict__ Whh_c, const ushort_t* __restrict__ Wih_c,
    const ushort_t* __restrict__ wfull_c, const ushort_t* __restrict__ bfull_c,
    const ushort_t* __restrict__ en_att, const ushort_t* __restrict__ feat_c,
    const float* __restrict__ ec, const int* __restrict__ lengths,
    const int* __restrict__ flag, void* __restrict__ out_base,
    ushort_t* __restrict__ h_bf, float* __restrict__ cbuf, float* __restrict__ de,
    float* __restrict__ fgate, float* __restrict__ hh, ushort_t* __restrict__ z_bf,
    ushort_t* __restrict__ H_all, unsigned* __restrict__ bar) {
    __shared__ __align__(16) char smem[65536];
    const int bid = blockIdx.x, tid = threadIdx.x;
    const int wave = tid >> 6, lane = tid & 63;
    const int quad = lane >> 4, l15 = lane & 15;
    ushort_t* tile = (ushort_t*)smem;

    const bool isA = bid < 48, isC = (bid >= 48 && bid < 80), isB = bid >= 80;
    float wf8[8];
    // ---- one-time staging ----
    if (!isB) {
        const int row = tid >> 2;
        const ushort_t* src;
        if (isA) {
            int n = (bid << 6) + row;
            src = (n < 512) ? (Wdec_c + n * 512)
                            : ((n < 1024) ? (Wfb_c + (n - 512) * 512)
                                          : (Whh_c + (n - 1024) * 512));
        } else {
            int nt = bid - 48;
            int j = (row >> 4) * 512 + nt * 16 + (row & 15);
            src = Wih_c + j * 1024 + 512;  // z-columns of W_ih
        }
        #pragma unroll
        for (int i = 0; i < 16; ++i) {
            int cb = ((tid & 3) << 4) + i;
            short8 v = *(const short8*)(src + (cb << 3));
            *(short8*)(tile + row * 512 + (((cb ^ (row & 15))) << 3)) = v;
        }
    } else {
        #pragma unroll
        for (int i = 0; i < 8; ++i) wf8[i] = bf2f(wfull_c[(lane << 3) + i]);
    }
    __syncthreads();

    const int f32o = *flag;
    const float bf0 = bf2f(bfull_c[0]);
    const int b_B = bid - 80;
    const int mylen = isB ? lengths[b_B] : 0;
    unsigned gen = 0;

    for (int t = 0; t < 31; ++t) {
        // ================= phase A =================
        if (isA) {
            f32x4 acc[4];
            #pragma unroll
            for (int s = 0; s < 4; ++s) acc[s] = (f32x4){0.f, 0.f, 0.f, 0.f};
            const ushort_t* ar = h_bf + ((wave << 4) + l15) * 512 + (quad << 3);
            short8 af[16];
            #pragma unroll
            for (int ki = 0; ki < 16; ++ki) af[ki] = *(const short8*)(ar + (ki << 5));
            #pragma unroll
            for (int ki = 0; ki < 16; ++ki) {
                int cb = (ki << 2) + quad;
                #pragma unroll
                for (int s = 0; s < 4; ++s) {
                    short8 bfr = *(const short8*)(tile + ((s << 4) + l15) * 512 +
                                                  ((cb ^ l15) << 3));
                    acc[s] = __builtin_amdgcn_mfma_f32_16x16x32_bf16(af[ki], bfr,
                                                                     acc[s], 0, 0, 0);
                }
            }
            const int n0 = bid << 6, mb = (wave << 4) + (quad << 2);
            #pragma unroll
            for (int s = 0; s < 4; ++s) {
                int n = n0 + (s << 4) + l15;
                #pragma unroll
                for (int r = 0; r < 4; ++r) {
                    int b = mb + r;
                    float v = acc[s][r];
                    if (n < 512)
                        de[b * 512 + n] = v + bf2f(bdec_c[n]);
                    else if (n < 1024)
                        fgate[b * 512 + (n - 512)] = sigmoidf_(v + bf2f(bfb_c[n - 512]));
                    else
                        hh[b * 2048 + (n - 1024)] = v;
                }
            }
        }
        grid_barrier(bar, gen++, isA, false);

        // ================= phase B =================
        if (isB) {
            float* fullv = (float*)smem;     // [224]
            float* red = fullv + 224;        // [8] (+pad)
            float* zpart = red + 32;         // [4][512]
            const size_t aoff = 19840000ull + ((size_t)b_B * 31 + t) * 196;
            const bool active = (mylen - 1) > t;
            if (!active) {
                if (tid < 196) {
                    if (f32o) ((float*)out_base)[aoff + tid] = 0.f;
                    else ((ushort_t*)out_base)[aoff + tid] = 0;
                }
            } else {
                float de8[8];
                #pragma unroll
                for (int i = 0; i < 8; ++i)
                    de8[i] = agent_ldf(&de[b_B * 512 + (lane << 3) + i]);
                const ushort_t* ea = en_att + b_B * 196 * 512 + (lane << 3);
                for (int l = wave; l < 196; l += 4) {
                    short8 ev = *(const short8*)(ea + l * 512);
                    float accv = 0.f;
                    #pragma unroll
                    for (int i = 0; i < 8; ++i)
                        accv += tanh_fast(bf2f((ushort_t)ev[i]) + de8[i]) * wf8[i];
                    accv = wred_sum(accv);
                    if (lane == 0) fullv[l] = accv + bf0;
                }
                __syncthreads();
                float v = (tid < 196) ? fullv[tid] : -1e30f;
                float wm = wred_max(v);
                if (lane == 0) red[wave] = wm;
                __syncthreads();
                float mx = fmaxf(fmaxf(red[0], red[1]), fmaxf(red[2], red[3]));
                float e = (tid < 196) ? __expf(v - mx) : 0.f;
                float sw = wred_sum(e);
                if (lane == 0) red[4 + wave] = sw;
                __syncthreads();
                float inv = 1.f / (red[4] + red[5] + red[6] + red[7]);
                if (tid < 196) {
                    float a = e * inv;
                    fullv[tid] = a;
                    if (f32o) ((float*)out_base)[aoff + tid] = a;
                    else ((ushort_t*)out_base)[aoff + tid] = f2bf(a);
                }
                __syncthreads();
                float z8[8] = {0.f, 0.f, 0.f, 0.f, 0.f, 0.f, 0.f, 0.f};
                const ushort_t* frb = feat_c + b_B * 196 * 512 + (lane << 3);
                for (int l = wave * 49; l < wave * 49 + 49; ++l) {
                    float a = fullv[l];
                    short8 fv = *(const short8*)(frb + l * 512);
                    #pragma unroll
                    for (int i = 0; i < 8; ++i) z8[i] += a * bf2f((ushort_t)fv[i]);
                }
                #pragma unroll
                for (int i = 0; i < 8; ++i)
                    zpart[wave * 512 + (lane << 3) + i] = z8[i];
                __syncthreads();
                #pragma unroll
                for (int q = 0; q < 2; ++q) {
                    int d = tid * 2 + q;
                    float zz = zpart[d] + zpart[512 + d] + zpart[1024 + d] +
                               zpart[1536 + d];
                    float g = agent_ldf(&fgate[b_B * 512 + d]);
                    z_bf[b_B * 512 + d] = f2bf(zz * g);
                }
                __syncthreads();
            }
        }
        grid_barrier(bar, gen++, isB, isC);

        // ================= phase C =================
        if (isC) {
            f32x4 acc[4];
            #pragma unroll
            for (int s = 0; s < 4; ++s) acc[s] = (f32x4){0.f, 0.f, 0.f, 0.f};
            const ushort_t* ar = z_bf + ((wave << 4) + l15) * 512 + (quad << 3);
            short8 af[16];
            #pragma unroll
            for (int ki = 0; ki < 16; ++ki) af[ki] = *(const short8*)(ar + (ki << 5));
            #pragma unroll
            for (int ki = 0; ki < 16; ++ki) {
                int cb = (ki << 2) + quad;
                #pragma unroll
                for (int s = 0; s < 4; ++s) {
                    short8 bfr = *(const short8*)(tile + ((s << 4) + l15) * 512 +
                                                  ((cb ^ l15) << 3));
                    acc[s] = __builtin_amdgcn_mfma_f32_16x16x32_bf16(af[ki], bfr,
                                                                     acc[s], 0, 0, 0);
                }
            }
            const int nt = bid - 48;
            const int dim = (nt << 4) + l15;
            const int mb = (wave << 4) + (quad << 2);
            #pragma unroll
            for (int r = 0; r < 4; ++r) {
                int b = mb + r;
                int eb = (t * 64 + b) * 2048, hb = b * 2048;
                float ig = acc[0][r] + ec[eb + dim] + hh[hb + dim];
                float fg = acc[1][r] + ec[eb + 512 + dim] + hh[hb + 512 + dim];
                float gg = acc[2][r] + ec[eb + 1024 + dim] + hh[hb + 1024 + dim];
                float og = acc[3][r] + ec[eb + 1536 + dim] + hh[hb + 1536 + dim];
                float co = cbuf[b * 512 + dim];
                float cn = sigmoidf_(fg) * co + sigmoidf_(ig) * tanh_fast(gg);
                float hn = sigmoidf_(og) * tanh_fast(cn);
                H_all[(t * 64 + b) * 512 + dim] = f2bf(hn);
                if (lengths[b] - 1 > t) {
                    cbuf[b * 512 + dim] = cn;
                    h_bf[b * 512 + dim] = f2bf(hn);
                }
            }
        }
        grid_barrier(bar, gen++, isC, isA);
    }
}

// ---- preds = H_all @ W_out.T + b_out; Wout tile LDS-resident, 8 t's/block ----
__global__ __launch_bounds__(256) void preds_kernel(
    const ushort_t* __restrict__ H_all, const ushort_t* __restrict__ Wout,
    const ushort_t* __restrict__ bout, const int* __restrict__ lengths,
    const int* __restrict__ flag, void* __restrict__ out_base) {
    __shared__ __align__(16) ushort_t tile[64 * 512];
    const int n0 = blockIdx.x << 6, tg = blockIdx.y;
    const int tid = threadIdx.x;
    const int wave = tid >> 6, lane = tid & 63;
    const int quad = lane >> 4, l15 = lane & 15;
    const int f32o = *flag;
    {
        const int row = tid >> 2;
        int n = n0 + row;
        const ushort_t* src = (n < 10000) ? (Wout + n * 512) : (const ushort_t*)nullptr;
        #pragma unroll
        for (int i = 0; i < 16; ++i) {
            int cb = ((tid & 3) << 4) + i;
            short8 v = {0, 0, 0, 0, 0, 0, 0, 0};
            if (src) v = *(const short8*)(src + (cb << 3));
            *(short8*)(tile + row * 512 + ((cb ^ (row & 15)) << 3)) = v;
        }
    }
    __syncthreads();
    for (int i = 0; i < 8; ++i) {
        int t = tg + (i << 2);
        if (t >= 31) break;
        f32x4 acc[4];
        #pragma unroll
        for (int s = 0; s < 4; ++s) acc[s] = (f32x4){0.f, 0.f, 0.f, 0.f};
        const ushort_t* ar = H_all + ((t * 64) + (wave << 4) + l15) * 512 + (quad << 3);
        short8 af[16];
        #pragma unroll
        for (int ki = 0; ki < 16; ++ki) af[ki] = *(const short8*)(ar + (ki << 5));
        #pragma unroll
        for (int ki = 0; ki < 16; ++ki) {
            int cb = (ki << 2) + quad;
            #pragma unroll
            for (int s = 0; s < 4; ++s) {
                short8 bfr = *(const short8*)(tile + ((s << 4) + l15) * 512 +
                                              ((cb ^ l15) << 3));
                acc[s] = __builtin_amdgcn_mfma_f32_16x16x32_bf16(af[ki], bfr,
                                                                 acc[s], 0, 0, 0);
            }
        }
        const int mb = (wave << 4) + (quad << 2);
        #pragma unroll
        for (int s = 0; s < 4; ++s) {
            int n = n0 + (s << 4) + l15;
            if (n >= 10000) continue;
            float bias = bf2f(bout[n]);
            #pragma unroll
            for (int r = 0; r < 4; ++r) {
                int b = mb + r;
                bool act = lengths[b] > t + 1;
                float val = act ? (acc[s][r] + bias) : 0.f;
                size_t off = (size_t)b * 310000 + t * 10000 + n;
                if (f32o) ((float*)out_base)[off] = val;
                else ((ushort_t*)out_base)[off] = act ? f2bf(val) : (ushort_t)0;
            }
        }
    }
}

extern "C" void kernel_launch(void* const* d_in, const int* in_sizes, int n_in,
                              void* d_out, int out_size, void* d_ws, size_t ws_size,
                              hipStream_t stream) {
    const void* features = d_in[0];
    const int* captions = (const int*)d_in[1];
    const int* lengths = (const int*)d_in[2];
    const void* W_emb = d_in[3];

    char* ws = (char*)d_ws;
    size_t o = 0;
    auto alloc = [&](size_t bytes) {
        size_t r = o;
        o += (bytes + 255) & ~(size_t)255;
        return r;
    };
    ushort_t* feat_c  = (ushort_t*)(ws + alloc(6422528ull * 2));
    ushort_t* Wenc_c  = (ushort_t*)(ws + alloc(262144ull * 2));
    ushort_t* benc_c  = (ushort_t*)(ws + alloc(512 * 2));
    ushort_t* Wdec_c  = (ushort_t*)(ws + alloc(262144ull * 2));
    ushort_t* bdec_c  = (ushort_t*)(ws + alloc(512 * 2));
    ushort_t* wfull_c = (ushort_t*)(ws + alloc(512 * 2));
    ushort_t* bfull_c = (ushort_t*)(ws + alloc(2));
    ushort_t* Wfb_c   = (ushort_t*)(ws + alloc(262144ull * 2));
    ushort_t* bfb_c   = (ushort_t*)(ws + alloc(512 * 2));
    ushort_t* Wih_c   = (ushort_t*)(ws + alloc(2097152ull * 2));
    ushort_t* Whh_c   = (ushort_t*)(ws + alloc(1048576ull * 2));
    ushort_t* bih_c   = (ushort_t*)(ws + alloc(2048 * 2));
    ushort_t* bhh_c   = (ushort_t*)(ws + alloc(2048 * 2));
    ushort_t* Wout_c  = (ushort_t*)(ws + alloc(5120000ull * 2));
    ushort_t* bout_c  = (ushort_t*)(ws + alloc(10000 * 2));
    ushort_t* Winh_c  = (ushort_t*)(ws + alloc(262144ull * 2));
    ushort_t* binh_c  = (ushort_t*)(ws + alloc(512 * 2));
    ushort_t* Winc_c  = (ushort_t*)(ws + alloc(262144ull * 2));
    ushort_t* binc_c  = (ushort_t*)(ws + alloc(512 * 2));
    ushort_t* emb_c   = (ushort_t*)(ws + alloc(1984ull * 512 * 2));
    ushort_t* en_att  = (ushort_t*)(ws + alloc(12544ull * 512 * 2));
    float*    ec      = (float*)(ws + alloc(1984ull * 2048 * 4));
    ushort_t* H_all   = (ushort_t*)(ws + alloc(1984ull * 512 * 2));
    ushort_t* h_bf    = (ushort_t*)(ws + alloc(64 * 512 * 2));
    float*    cbuf    = (float*)(ws + alloc(64 * 512 * 4));
    float*    de      = (float*)(ws + alloc(64 * 512 * 4));
    float*    fgate   = (float*)(ws + alloc(64 * 512 * 4));
    float*    hh      = (float*)(ws + alloc(64ull * 2048 * 4));
    ushort_t* z_bf    = (ushort_t*)(ws + alloc(64 * 512 * 2));
    ushort_t* mean_bf = (ushort_t*)(ws + alloc(64 * 512 * 2));
    int*      flag    = (int*)(ws + alloc(256));
    unsigned* bar     = (unsigned*)(ws + alloc(4096));

    detect_kernel<<<1, 64, 0, stream>>>((const unsigned*)features, flag);
    bar_init<<<1, 1024, 0, stream>>>(bar);

    CvtArgs ca;
    const void* srcs[NCVT] = {features, d_in[4], d_in[5], d_in[6], d_in[7], d_in[8],
                              d_in[9], d_in[10], d_in[11], d_in[12], d_in[13], d_in[14],
                              d_in[15], d_in[16], d_in[17], d_in[18], d_in[19], d_in[20],
                              d_in[21]};
    void* dsts[NCVT] = {feat_c, Wenc_c, benc_c, Wdec_c, bdec_c, wfull_c, bfull_c,
                        Wfb_c, bfb_c, Wih_c, Whh_c, bih_c, bhh_c, Wout_c, bout_c,
                        Winh_c, binh_c, Winc_c, binc_c};
    int ns[NCVT] = {6422528, 262144, 512, 262144, 512, 512, 1, 262144, 512,
                    2097152, 1048576, 2048, 2048, 5120000, 10000, 262144, 512,
                    262144, 512};
    for (int i = 0; i < NCVT; ++i) {
        ca.src[i] = srcs[i];
        ca.dst[i] = dsts[i];
        ca.n[i] = ns[i];
    }
    convert_kernel<<<dim3(3136, NCVT), 256, 0, stream>>>(ca, flag);
    embrows_kernel<<<1984, 256, 0, stream>>>(W_emb, captions, flag, emb_c);

    mean_kernel<<<64, 256, 0, stream>>>(feat_c, mean_bf);
    init_kernel<<<16, 256, 0, stream>>>(mean_bf, Winh_c, binh_c, Winc_c, binc_c,
                                        h_bf, cbuf);
    enatt_kernel<<<dim3(8, 196), 256, 0, stream>>>(feat_c, Wenc_c, benc_c, en_att);
    ec_kernel<<<dim3(32, 31), 256, 0, stream>>>(emb_c, Wih_c, bih_c, bhh_c, ec);

    fused_loop<<<NBLK, 256, 0, stream>>>(Wdec_c, bdec_c, Wfb_c, bfb_c, Whh_c, Wih_c,
                                         wfull_c, bfull_c, en_att, feat_c, ec,
                                         lengths, flag, d_out, h_bf, cbuf, de, fgate,
                                         hh, z_bf, H_all, bar);

    preds_kernel<<<dim3(157, 4), 256, 0, stream>>>(H_all, Wout_c, bout_c, lengths,
                                                   flag, d_out);
}

// Round 5
// 2420.226 us; speedup vs baseline: 2.1998x; 1.0093x over previous
//
#include <hip/hip_runtime.h>

// DecoderLSTM (show-attend-tell) for MI355X. R5: persistent fused recurrence
// with a FENCELESS grid barrier (relaxed monotonic counters only). All
// cross-role traffic bypasses L2: de/fgate/hh via relaxed agent atomics both
// sides; z/h pushed with bypass stores into PER-STEP rotating buffers so
// consumers use normal cached vector loads at fresh addresses (no stale-line
// hazard, no invalidates). L2 stays warm for en_att/feat/ec/weights.
// B=64 T=32 F=512 L=196 E=512 H=512 A=512 V=10000, Tmax=31.

typedef unsigned short ushort_t;
typedef __attribute__((ext_vector_type(8))) short short8;
typedef __attribute__((ext_vector_type(4))) float f32x4;

__device__ __forceinline__ float bf2f(ushort_t u) {
    unsigned x = ((unsigned)u) << 16;
    float f;
    __builtin_memcpy(&f, &x, 4);
    return f;
}
__device__ __forceinline__ ushort_t f2bf(float f) {
    unsigned x;
    __builtin_memcpy(&x, &f, 4);
    unsigned r = (x + 0x7fffu + ((x >> 16) & 1u)) >> 16;
    return (ushort_t)r;
}
__device__ __forceinline__ float sigmoidf_(float x) { return 1.f / (1.f + __expf(-x)); }
__device__ __forceinline__ float tanh_fast(float x) {
    float e = __expf(2.f * x);
    return 1.f - 2.f / (e + 1.f);
}
__device__ __forceinline__ float wred_sum(float v) {
    #pragma unroll
    for (int m = 32; m; m >>= 1) v += __shfl_xor(v, m, 64);
    return v;
}
__device__ __forceinline__ float wred_max(float v) {
    #pragma unroll
    for (int m = 32; m; m >>= 1) v = fmaxf(v, __shfl_xor(v, m, 64));
    return v;
}
__device__ __forceinline__ float agent_ldf(const float* p) {
    return __hip_atomic_load((float*)p, __ATOMIC_RELAXED, __HIP_MEMORY_SCOPE_AGENT);
}
__device__ __forceinline__ void agent_stf(float* p, float v) {
    __hip_atomic_store(p, v, __ATOMIC_RELAXED, __HIP_MEMORY_SCOPE_AGENT);
}
__device__ __forceinline__ void agent_stu(unsigned* p, unsigned v) {
    __hip_atomic_store(p, v, __ATOMIC_RELAXED, __HIP_MEMORY_SCOPE_AGENT);
}

// ---- dtype detection ----
__global__ void detect_kernel(const unsigned* __restrict__ feat_raw, int* __restrict__ flag) {
    int lane = threadIdx.x;
    unsigned u = feat_raw[lane];
    unsigned e = (u >> 7) & 0xffu;
    bool bf_like = (e >= 105 && e <= 133);
    unsigned long long m = __ballot(bf_like);
    if (lane == 0) *flag = (__popcll(m) >= 40) ? 0 : 1;  // 1 -> fp32 inputs
}

__global__ void bar_init(unsigned* __restrict__ bar) { bar[threadIdx.x] = 0u; }

#define NCVT 19
struct CvtArgs {
    const void* src[NCVT];
    void* dst[NCVT];
    int n[NCVT];
};

__global__ __launch_bounds__(256) void convert_kernel(CvtArgs a, const int* __restrict__ flag) {
    const int ai = blockIdx.y;
    const int n = a.n[ai];
    const int base = (blockIdx.x * 256 + threadIdx.x) * 8;
    if (base >= n) return;
    ushort_t* dst = (ushort_t*)a.dst[ai];
    if (*flag) {
        const float* s = (const float*)a.src[ai];
        #pragma unroll
        for (int i = 0; i < 8; ++i) {
            int idx = base + i;
            if (idx < n) dst[idx] = f2bf(s[idx]);
        }
    } else {
        const ushort_t* s = (const ushort_t*)a.src[ai];
        #pragma unroll
        for (int i = 0; i < 8; ++i) {
            int idx = base + i;
            if (idx < n) dst[idx] = s[idx];
        }
    }
}

// ---- gather needed embedding rows -> bf16 [31*64, 512] ----
__global__ __launch_bounds__(256) void embrows_kernel(const void* __restrict__ Wemb,
                                                      const int* __restrict__ captions,
                                                      const int* __restrict__ flag,
                                                      ushort_t* __restrict__ emb_c) {
    const int tb = blockIdx.x;
    const int t = tb >> 6, b = tb & 63;
    const int cap = captions[b * 32 + t];
    const int e0 = threadIdx.x;
    if (*flag) {
        const float* s = (const float*)Wemb + cap * 512;
        emb_c[tb * 512 + e0] = f2bf(s[e0]);
        emb_c[tb * 512 + e0 + 256] = f2bf(s[e0 + 256]);
    } else {
        const ushort_t* s = (const ushort_t*)Wemb + cap * 512;
        emb_c[tb * 512 + e0] = s[e0];
        emb_c[tb * 512 + e0 + 256] = s[e0 + 256];
    }
}

// ---- generic 64x64 MFMA tile (pre-pass GEMMs) ----
template <class AROW, class BROW, class EPI>
__device__ __forceinline__ void gemm_tile(AROW arow, BROW brow, EPI epi) {
    __shared__ __align__(16) ushort_t As[64][40];
    __shared__ __align__(16) ushort_t Bs[64][40];
    const int tid = threadIdx.x;
    const int row = tid >> 2, ks = (tid & 3) << 3;
    const int wave = tid >> 6, lane = tid & 63;
    const int quad = lane >> 4, l15 = lane & 15;
    f32x4 acc[4];
    #pragma unroll
    for (int s = 0; s < 4; ++s) acc[s] = (f32x4){0.f, 0.f, 0.f, 0.f};
    const ushort_t* ap = arow(row);
    const ushort_t* bp = brow(row);
    for (int k0 = 0; k0 < 512; k0 += 32) {
        short8 av = {0, 0, 0, 0, 0, 0, 0, 0};
        short8 bv = {0, 0, 0, 0, 0, 0, 0, 0};
        if (ap) av = *(const short8*)(ap + k0 + ks);
        if (bp) bv = *(const short8*)(bp + k0 + ks);
        __syncthreads();
        *(short8*)&As[row][ks] = av;
        *(short8*)&Bs[row][ks] = bv;
        __syncthreads();
        short8 af = *(const short8*)&As[(wave << 4) + l15][quad << 3];
        #pragma unroll
        for (int s = 0; s < 4; ++s) {
            short8 bfr = *(const short8*)&Bs[(s << 4) + l15][quad << 3];
            acc[s] = __builtin_amdgcn_mfma_f32_16x16x32_bf16(af, bfr, acc[s], 0, 0, 0);
        }
    }
    epi((wave << 4) + (quad << 2), l15, acc);
}

// ---- mean over L of features [B, F, L] -> bf16 [B, F] ----
__global__ __launch_bounds__(256) void mean_kernel(const ushort_t* __restrict__ features,
                                                   ushort_t* __restrict__ mean_bf) {
    const int b = blockIdx.x;
    const int wave = threadIdx.x >> 6, lane = threadIdx.x & 63;
    const ushort_t* fb = features + b * 512 * 196;
    for (int f = wave; f < 512; f += 4) {
        const ushort_t* r = fb + f * 196;
        float s = bf2f(r[lane]) + bf2f(r[lane + 64]) + bf2f(r[lane + 128]);
        if (lane < 4) s += bf2f(r[lane + 192]);
        s = wred_sum(s);
        if (lane == 0) mean_bf[b * 512 + f] = f2bf(s * (1.f / 196.f));
    }
}

// ---- h0 / c0 : h0 -> h_t[0] (f32), c0 -> cbuf ----
__global__ __launch_bounds__(256) void init_kernel(
    const ushort_t* __restrict__ mean_bf, const ushort_t* __restrict__ Winh,
    const ushort_t* __restrict__ binh, const ushort_t* __restrict__ Winc,
    const ushort_t* __restrict__ binc, float* __restrict__ h_t,
    float* __restrict__ cbuf) {
    const int n0 = blockIdx.x << 6;
    gemm_tile(
        [&](int r) { return mean_bf + r * 512; },
        [&](int r) {
            int n = n0 + r;
            return (n < 512) ? (Winh + n * 512) : (Winc + (n - 512) * 512);
        },
        [&](int mb, int l15, const f32x4* acc) {
            #pragma unroll
            for (int s = 0; s < 4; ++s) {
                int n = n0 + (s << 4) + l15;
                #pragma unroll
                for (int r = 0; r < 4; ++r) {
                    int b = mb + r;
                    if (n < 512)
                        h_t[b * 512 + n] = acc[s][r] + bf2f(binh[n]);
                    else
                        cbuf[b * 512 + (n - 512)] = acc[s][r] + bf2f(binc[n - 512]);
                }
            }
        });
}

// ---- en_att = feat_r @ W_enc.T + b_enc -> bf16 [12544, 512] ----
__global__ __launch_bounds__(256) void enatt_kernel(const ushort_t* __restrict__ feat,
                                                    const ushort_t* __restrict__ Wenc,
                                                    const ushort_t* __restrict__ benc,
                                                    ushort_t* __restrict__ en_att) {
    const int m0 = blockIdx.y << 6, n0 = blockIdx.x << 6;
    gemm_tile(
        [&](int r) { return feat + (m0 + r) * 512; },
        [&](int r) { return Wenc + (n0 + r) * 512; },
        [&](int mb, int l15, const f32x4* acc) {
            #pragma unroll
            for (int s = 0; s < 4; ++s) {
                int n = n0 + (s << 4) + l15;
                float bias = bf2f(benc[n]);
                #pragma unroll
                for (int r = 0; r < 4; ++r) {
                    int m = m0 + mb + r;
                    en_att[m * 512 + n] = f2bf(acc[s][r] + bias);
                }
            }
        });
}

// ---- ec[t,b,j] = emb_row @ W_ih[:, :512].T + b_ih + b_hh -> fp32 ----
__global__ __launch_bounds__(256) void ec_kernel(const ushort_t* __restrict__ emb_c,
                                                 const ushort_t* __restrict__ Wih,
                                                 const ushort_t* __restrict__ bih,
                                                 const ushort_t* __restrict__ bhh,
                                                 float* __restrict__ ec) {
    const int t = blockIdx.y, n0 = blockIdx.x << 6;
    gemm_tile(
        [&](int r) { return emb_c + (t * 64 + r) * 512; },
        [&](int r) { return Wih + (n0 + r) * 1024; },
        [&](int mb, int l15, const f32x4* acc) {
            #pragma unroll
            for (int s = 0; s < 4; ++s) {
                int j = n0 + (s << 4) + l15;
                float bias = bf2f(bih[j]) + bf2f(bhh[j]);
                #pragma unroll
                for (int r = 0; r < 4; ++r) {
                    int b = mb + r;
                    ec[(t * 64 + b) * 2048 + j] = acc[s][r] + bias;
                }
            }
        });
}

// ================== fused persistent recurrence kernel ==================
// 144 blocks x 256. 0..47: stepA GEMM (LDS-resident [Wdec;Wfb;Whh] tile);
// 48..79: stepC GEMM (LDS-resident W_ih z-cols, [i,f,g,o]x16 rows);
// 80..143: attention for batch b = bid-80.
#define NBLK 144

// Fenceless barrier: monotonic relaxed counters; __syncthreads drains vmcnt
// (pushes ack'd at coherence point) before the signal RMW. No wbl2/inv.
__device__ __forceinline__ void grid_barrier(unsigned* bar, unsigned gen) {
    __syncthreads();
    if (threadIdx.x == 0) {
        const int grp = blockIdx.x & 7;
        unsigned prev = __hip_atomic_fetch_add(&bar[grp << 5], 1u, __ATOMIC_RELAXED,
                                               __HIP_MEMORY_SCOPE_AGENT);
        if (prev == (gen + 1) * (NBLK / 8) - 1) {
            unsigned pr = __hip_atomic_fetch_add(&bar[8 << 5], 1u, __ATOMIC_RELAXED,
                                                 __HIP_MEMORY_SCOPE_AGENT);
            if (pr == (gen + 1) * 8 - 1) {
                #pragma unroll
                for (int g = 0; g < 8; ++g)
                    agent_stu(&bar[(9 + g) << 5], gen + 1);
            }
        }
        long cap = 0;
        while (__hip_atomic_load(&bar[(9 + grp) << 5], __ATOMIC_RELAXED,
                                 __HIP_MEMORY_SCOPE_AGENT) <= gen) {
            __builtin_amdgcn_s_sleep(8);
            if (++cap > (1l << 21)) break;  // bail -> wrong answer, not hang
        }
    }
    __syncthreads();
}

__global__ __launch_bounds__(256) void fused_loop(
    const ushort_t* __restrict__ Wdec_c, const ushort_t* __restrict__ bdec_c,
    const ushort_t* __restrict__ Wfb_c, const ushort_t* __restrict__ bfb_c,
    const ushort_t* __restrict__ Whh_c, const ushort_t* __restrict__ Wih_c,
    const ushort_t* __restrict__ wfull_c, const ushort_t* __restrict__ bfull_c,
    const ushort_t* __restrict__ en_att, const ushort_t* __restrict__ feat_c,
    const float* __restrict__ ec, const int* __restrict__ lengths,
    const int* __restrict__ flag, void* __restrict__ out_base,
    float* __restrict__ h_t,   // [32][64*512] f32, rotating (pushed)
    ushort_t* __restrict__ z_t,  // [31][64*512] bf16, rotating (pushed)
    float* __restrict__ cbuf, float* __restrict__ de, float* __restrict__ fgate,
    float* __restrict__ hh, ushort_t* __restrict__ H_all,
    unsigned* __restrict__ bar) {
    __shared__ __align__(16) char smem[65536];
    const int bid = blockIdx.x, tid = threadIdx.x;
    const int wave = tid >> 6, lane = tid & 63;
    const int quad = lane >> 4, l15 = lane & 15;
    ushort_t* tile = (ushort_t*)smem;

    const bool isA = bid < 48, isC = (bid >= 48 && bid < 80), isB = bid >= 80;
    float wf8[8];
    // ---- one-time staging ----
    if (!isB) {
        const int row = tid >> 2;
        const ushort_t* src;
        if (isA) {
            int n = (bid << 6) + row;
            src = (n < 512) ? (Wdec_c + n * 512)
                            : ((n < 1024) ? (Wfb_c + (n - 512) * 512)
                                          : (Whh_c + (n - 1024) * 512));
        } else {
            int nt = bid - 48;
            int j = (row >> 4) * 512 + nt * 16 + (row & 15);
            src = Wih_c + j * 1024 + 512;  // z-columns of W_ih
        }
        #pragma unroll
        for (int i = 0; i < 16; ++i) {
            int cb = ((tid & 3) << 4) + i;
            short8 v = *(const short8*)(src + (cb << 3));
            *(short8*)(tile + row * 512 + (((cb ^ (row & 15))) << 3)) = v;
        }
    } else {
        #pragma unroll
        for (int i = 0; i < 8; ++i) wf8[i] = bf2f(wfull_c[(lane << 3) + i]);
    }
    __syncthreads();

    const int f32o = *flag;
    const float bf0 = bf2f(bfull_c[0]);
    const int b_B = bid - 80;
    const int mylen = isB ? lengths[b_B] : 0;
    unsigned gen = 0;

    for (int t = 0; t < 31; ++t) {
        // ================= phase A =================
        if (isA) {
            f32x4 acc[4];
            #pragma unroll
            for (int s = 0; s < 4; ++s) acc[s] = (f32x4){0.f, 0.f, 0.f, 0.f};
            // h fragments: cached f32 loads from fresh per-step buffer -> bf16
            const float* hr = h_t + t * 32768 + ((wave << 4) + l15) * 512 + (quad << 3);
            short8 af[16];
            #pragma unroll
            for (int ki = 0; ki < 16; ++ki) {
                f32x4 a0 = *(const f32x4*)(hr + (ki << 5));
                f32x4 a1 = *(const f32x4*)(hr + (ki << 5) + 4);
                #pragma unroll
                for (int i = 0; i < 4; ++i) {
                    af[ki][i] = (short)f2bf(a0[i]);
                    af[ki][4 + i] = (short)f2bf(a1[i]);
                }
            }
            #pragma unroll
            for (int ki = 0; ki < 16; ++ki) {
                int cb = (ki << 2) + quad;
                #pragma unroll
                for (int s = 0; s < 4; ++s) {
                    short8 bfr = *(const short8*)(tile + ((s << 4) + l15) * 512 +
                                                  ((cb ^ l15) << 3));
                    acc[s] = __builtin_amdgcn_mfma_f32_16x16x32_bf16(af[ki], bfr,
                                                                     acc[s], 0, 0, 0);
                }
            }
            const int n0 = bid << 6, mb = (wave << 4) + (quad << 2);
            #pragma unroll
            for (int s = 0; s < 4; ++s) {
                int n = n0 + (s << 4) + l15;
                #pragma unroll
                for (int r = 0; r < 4; ++r) {
                    int b = mb + r;
                    float v = acc[s][r];
                    if (n < 512)
                        agent_stf(&de[b * 512 + n], v + bf2f(bdec_c[n]));
                    else if (n < 1024)
                        agent_stf(&fgate[b * 512 + (n - 512)],
                                  sigmoidf_(v + bf2f(bfb_c[n - 512])));
                    else
                        agent_stf(&hh[b * 2048 + (n - 1024)], v);
                }
            }
        }
        grid_barrier(bar, gen++);

        // ================= phase B =================
        if (isB) {
            float* fullv = (float*)smem;     // [224]
            float* red = fullv + 224;        // [8] (+pad)
            float* zpart = red + 32;         // [4][512]
            const size_t aoff = 19840000ull + ((size_t)b_B * 31 + t) * 196;
            const bool active = (mylen - 1) > t;
            if (!active) {
                if (tid < 196) {
                    if (f32o) ((float*)out_base)[aoff + tid] = 0.f;
                    else ((ushort_t*)out_base)[aoff + tid] = 0;
                }
            } else {
                float de8[8];
                #pragma unroll
                for (int i = 0; i < 8; ++i)
                    de8[i] = agent_ldf(&de[b_B * 512 + (lane << 3) + i]);
                const ushort_t* ea = en_att + b_B * 196 * 512 + (lane << 3);
                for (int l = wave; l < 196; l += 4) {
                    short8 ev = *(const short8*)(ea + l * 512);
                    float accv = 0.f;
                    #pragma unroll
                    for (int i = 0; i < 8; ++i)
                        accv += tanh_fast(bf2f((ushort_t)ev[i]) + de8[i]) * wf8[i];
                    accv = wred_sum(accv);
                    if (lane == 0) fullv[l] = accv + bf0;
                }
                __syncthreads();
                float v = (tid < 196) ? fullv[tid] : -1e30f;
                float wm = wred_max(v);
                if (lane == 0) red[wave] = wm;
                __syncthreads();
                float mx = fmaxf(fmaxf(red[0], red[1]), fmaxf(red[2], red[3]));
                float e = (tid < 196) ? __expf(v - mx) : 0.f;
                float sw = wred_sum(e);
                if (lane == 0) red[4 + wave] = sw;
                __syncthreads();
                float inv = 1.f / (red[4] + red[5] + red[6] + red[7]);
                if (tid < 196) {
                    float a = e * inv;
                    fullv[tid] = a;
                    if (f32o) ((float*)out_base)[aoff + tid] = a;
                    else ((ushort_t*)out_base)[aoff + tid] = f2bf(a);
                }
                __syncthreads();
                float z8[8] = {0.f, 0.f, 0.f, 0.f, 0.f, 0.f, 0.f, 0.f};
                const ushort_t* frb = feat_c + b_B * 196 * 512 + (lane << 3);
                for (int l = wave * 49; l < wave * 49 + 49; ++l) {
                    float a = fullv[l];
                    short8 fv = *(const short8*)(frb + l * 512);
                    #pragma unroll
                    for (int i = 0; i < 8; ++i) z8[i] += a * bf2f((ushort_t)fv[i]);
                }
                #pragma unroll
                for (int i = 0; i < 8; ++i)
                    zpart[wave * 512 + (lane << 3) + i] = z8[i];
                __syncthreads();
                int d0 = tid << 1;
                float zz0 = zpart[d0] + zpart[512 + d0] + zpart[1024 + d0] +
                            zpart[1536 + d0];
                float zz1 = zpart[d0 + 1] + zpart[513 + d0] + zpart[1025 + d0] +
                            zpart[1537 + d0];
                zz0 *= agent_ldf(&fgate[b_B * 512 + d0]);
                zz1 *= agent_ldf(&fgate[b_B * 512 + d0 + 1]);
                unsigned pk = (unsigned)f2bf(zz0) | ((unsigned)f2bf(zz1) << 16);
                agent_stu((unsigned*)(z_t + t * 32768 + b_B * 512) + tid, pk);
                __syncthreads();
            }
        }
        grid_barrier(bar, gen++);

        // ================= phase C =================
        if (isC) {
            const int nt = bid - 48;
            const int dim = (nt << 4) + l15;
            const int mb = (wave << 4) + (quad << 2);
            // prefetch hh (bypass loads) early to hide coherence-point latency
            float hhv[4][4];
            #pragma unroll
            for (int r = 0; r < 4; ++r)
                #pragma unroll
                for (int g = 0; g < 4; ++g)
                    hhv[g][r] = agent_ldf(&hh[(mb + r) * 2048 + g * 512 + dim]);
            f32x4 acc[4];
            #pragma unroll
            for (int s = 0; s < 4; ++s) acc[s] = (f32x4){0.f, 0.f, 0.f, 0.f};
            const ushort_t* ar = z_t + t * 32768 + ((wave << 4) + l15) * 512 +
                                 (quad << 3);
            short8 af[16];
            #pragma unroll
            for (int ki = 0; ki < 16; ++ki) af[ki] = *(const short8*)(ar + (ki << 5));
            #pragma unroll
            for (int ki = 0; ki < 16; ++ki) {
                int cb = (ki << 2) + quad;
                #pragma unroll
                for (int s = 0; s < 4; ++s) {
                    short8 bfr = *(const short8*)(tile + ((s << 4) + l15) * 512 +
                                                  ((cb ^ l15) << 3));
                    acc[s] = __builtin_amdgcn_mfma_f32_16x16x32_bf16(af[ki], bfr,
                                                                     acc[s], 0, 0, 0);
                }
            }
            #pragma unroll
            for (int r = 0; r < 4; ++r) {
                int b = mb + r;
                int eb = (t * 64 + b) * 2048;
                float ig = acc[0][r] + ec[eb + dim] + hhv[0][r];
                float fg = acc[1][r] + ec[eb + 512 + dim] + hhv[1][r];
                float gg = acc[2][r] + ec[eb + 1024 + dim] + hhv[2][r];
                float og = acc[3][r] + ec[eb + 1536 + dim] + hhv[3][r];
                float co = cbuf[b * 512 + dim];
                float cn = sigmoidf_(fg) * co + sigmoidf_(ig) * tanh_fast(gg);
                float hn = sigmoidf_(og) * tanh_fast(cn);
                H_all[(t * 64 + b) * 512 + dim] = f2bf(hn);
                bool act = lengths[b] - 1 > t;
                float hold = h_t[t * 32768 + b * 512 + dim];  // cached, fresh addr
                cbuf[b * 512 + dim] = act ? cn : co;
                agent_stf(&h_t[(t + 1) * 32768 + b * 512 + dim], act ? hn : hold);
            }
        }
        grid_barrier(bar, gen++);
    }
}

// ---- preds = H_all @ W_out.T + b_out; Wout tile LDS-resident, 8 t's/block ----
__global__ __launch_bounds__(256) void preds_kernel(
    const ushort_t* __restrict__ H_all, const ushort_t* __restrict__ Wout,
    const ushort_t* __restrict__ bout, const int* __restrict__ lengths,
    const int* __restrict__ flag, void* __restrict__ out_base) {
    __shared__ __align__(16) ushort_t tile[64 * 512];
    const int n0 = blockIdx.x << 6, tg = blockIdx.y;
    const int tid = threadIdx.x;
    const int wave = tid >> 6, lane = tid & 63;
    const int quad = lane >> 4, l15 = lane & 15;
    const int f32o = *flag;
    {
        const int row = tid >> 2;
        int n = n0 + row;
        const ushort_t* src = (n < 10000) ? (Wout + n * 512) : (const ushort_t*)nullptr;
        #pragma unroll
        for (int i = 0; i < 16; ++i) {
            int cb = ((tid & 3) << 4) + i;
            short8 v = {0, 0, 0, 0, 0, 0, 0, 0};
            if (src) v = *(const short8*)(src + (cb << 3));
            *(short8*)(tile + row * 512 + ((cb ^ (row & 15)) << 3)) = v;
        }
    }
    __syncthreads();
    for (int i = 0; i < 8; ++i) {
        int t = tg + (i << 2);
        if (t >= 31) break;
        f32x4 acc[4];
        #pragma unroll
        for (int s = 0; s < 4; ++s) acc[s] = (f32x4){0.f, 0.f, 0.f, 0.f};
        const ushort_t* ar = H_all + ((t * 64) + (wave << 4) + l15) * 512 + (quad << 3);
        short8 af[16];
        #pragma unroll
        for (int ki = 0; ki < 16; ++ki) af[ki] = *(const short8*)(ar + (ki << 5));
        #pragma unroll
        for (int ki = 0; ki < 16; ++ki) {
            int cb = (ki << 2) + quad;
            #pragma unroll
            for (int s = 0; s < 4; ++s) {
                short8 bfr = *(const short8*)(tile + ((s << 4) + l15) * 512 +
                                              ((cb ^ l15) << 3));
                acc[s] = __builtin_amdgcn_mfma_f32_16x16x32_bf16(af[ki], bfr,
                                                                 acc[s], 0, 0, 0);
            }
        }
        const int mb = (wave << 4) + (quad << 2);
        #pragma unroll
        for (int s = 0; s < 4; ++s) {
            int n = n0 + (s << 4) + l15;
            if (n >= 10000) continue;
            float bias = bf2f(bout[n]);
            #pragma unroll
            for (int r = 0; r < 4; ++r) {
                int b = mb + r;
                bool act = lengths[b] > t + 1;
                float val = act ? (acc[s][r] + bias) : 0.f;
                size_t off = (size_t)b * 310000 + t * 10000 + n;
                if (f32o) ((float*)out_base)[off] = val;
                else ((ushort_t*)out_base)[off] = act ? f2bf(val) : (ushort_t)0;
            }
        }
    }
}

extern "C" void kernel_launch(void* const* d_in, const int* in_sizes, int n_in,
                              void* d_out, int out_size, void* d_ws, size_t ws_size,
                              hipStream_t stream) {
    const void* features = d_in[0];
    const int* captions = (const int*)d_in[1];
    const int* lengths = (const int*)d_in[2];
    const void* W_emb = d_in[3];

    char* ws = (char*)d_ws;
    size_t o = 0;
    auto alloc = [&](size_t bytes) {
        size_t r = o;
        o += (bytes + 255) & ~(size_t)255;
        return r;
    };
    ushort_t* feat_c  = (ushort_t*)(ws + alloc(6422528ull * 2));
    ushort_t* Wenc_c  = (ushort_t*)(ws + alloc(262144ull * 2));
    ushort_t* benc_c  = (ushort_t*)(ws + alloc(512 * 2));
    ushort_t* Wdec_c  = (ushort_t*)(ws + alloc(262144ull * 2));
    ushort_t* bdec_c  = (ushort_t*)(ws + alloc(512 * 2));
    ushort_t* wfull_c = (ushort_t*)(ws + alloc(512 * 2));
    ushort_t* bfull_c = (ushort_t*)(ws + alloc(2));
    ushort_t* Wfb_c   = (ushort_t*)(ws + alloc(262144ull * 2));
    ushort_t* bfb_c   = (ushort_t*)(ws + alloc(512 * 2));
    ushort_t* Wih_c   = (ushort_t*)(ws + alloc(2097152ull * 2));
    ushort_t* Whh_c   = (ushort_t*)(ws + alloc(1048576ull * 2));
    ushort_t* bih_c   = (ushort_t*)(ws + alloc(2048 * 2));
    ushort_t* bhh_c   = (ushort_t*)(ws + alloc(2048 * 2));
    ushort_t* Wout_c  = (ushort_t*)(ws + alloc(5120000ull * 2));
    ushort_t* bout_c  = (ushort_t*)(ws + alloc(10000 * 2));
    ushort_t* Winh_c  = (ushort_t*)(ws + alloc(262144ull * 2));
    ushort_t* binh_c  = (ushort_t*)(ws + alloc(512 * 2));
    ushort_t* Winc_c  = (ushort_t*)(ws + alloc(262144ull * 2));
    ushort_t* binc_c  = (ushort_t*)(ws + alloc(512 * 2));
    ushort_t* emb_c   = (ushort_t*)(ws + alloc(1984ull * 512 * 2));
    ushort_t* en_att  = (ushort_t*)(ws + alloc(12544ull * 512 * 2));
    float*    ec      = (float*)(ws + alloc(1984ull * 2048 * 4));
    ushort_t* H_all   = (ushort_t*)(ws + alloc(1984ull * 512 * 2));
    float*    h_t     = (float*)(ws + alloc(32ull * 32768 * 4));   // 4 MB rotating
    ushort_t* z_t     = (ushort_t*)(ws + alloc(31ull * 32768 * 2)); // 2 MB rotating
    float*    cbuf    = (float*)(ws + alloc(64 * 512 * 4));
    float*    de      = (float*)(ws + alloc(64 * 512 * 4));
    float*    fgate   = (float*)(ws + alloc(64 * 512 * 4));
    float*    hh      = (float*)(ws + alloc(64ull * 2048 * 4));
    ushort_t* mean_bf = (ushort_t*)(ws + alloc(64 * 512 * 2));
    int*      flag    = (int*)(ws + alloc(256));
    unsigned* bar     = (unsigned*)(ws + alloc(4096));

    detect_kernel<<<1, 64, 0, stream>>>((const unsigned*)features, flag);
    bar_init<<<1, 1024, 0, stream>>>(bar);

    CvtArgs ca;
    const void* srcs[NCVT] = {features, d_in[4], d_in[5], d_in[6], d_in[7], d_in[8],
                              d_in[9], d_in[10], d_in[11], d_in[12], d_in[13], d_in[14],
                              d_in[15], d_in[16], d_in[17], d_in[18], d_in[19], d_in[20],
                              d_in[21]};
    void* dsts[NCVT] = {feat_c, Wenc_c, benc_c, Wdec_c, bdec_c, wfull_c, bfull_c,
                        Wfb_c, bfb_c, Wih_c, Whh_c, bih_c, bhh_c, Wout_c, bout_c,
                        Winh_c, binh_c, Winc_c, binc_c};
    int ns[NCVT] = {6422528, 262144, 512, 262144, 512, 512, 1, 262144, 512,
                    2097152, 1048576, 2048, 2048, 5120000, 10000, 262144, 512,
                    262144, 512};
    for (int i = 0; i < NCVT; ++i) {
        ca.src[i] = srcs[i];
        ca.dst[i] = dsts[i];
        ca.n[i] = ns[i];
    }
    convert_kernel<<<dim3(3136, NCVT), 256, 0, stream>>>(ca, flag);
    embrows_kernel<<<1984, 256, 0, stream>>>(W_emb, captions, flag, emb_c);

    mean_kernel<<<64, 256, 0, stream>>>(feat_c, mean_bf);
    init_kernel<<<16, 256, 0, stream>>>(mean_bf, Winh_c, binh_c, Winc_c, binc_c,
                                        h_t, cbuf);
    enatt_kernel<<<dim3(8, 196), 256, 0, stream>>>(feat_c, Wenc_c, benc_c, en_att);
    ec_kernel<<<dim3(32, 31), 256, 0, stream>>>(emb_c, Wih_c, bih_c, bhh_c, ec);

    fused_loop<<<NBLK, 256, 0, stream>>>(Wdec_c, bdec_c, Wfb_c, bfb_c, Whh_c, Wih_c,
                                         wfull_c, bfull_c, en_att, feat_c, ec,
                                         lengths, flag, d_out, h_t, z_t, cbuf, de,
                                         fgate, hh, H_all, bar);

    preds_kernel<<<dim3(157, 4), 256, 0, stream>>>(H_all, Wout_c, bout_c, lengths,
                                                   flag, d_out);
}